// Round 17
// baseline (124.315 us; speedup 1.0000x reference)
//
#include <hip/hip_runtime.h>
#include <hip/hip_bf16.h>
#include <stdint.h>

#define NN 2048
#define DD 1024
#define HH 16
#define HDD 64
#define QBLK 64
#define KVBLK 64

typedef unsigned short u16;
typedef __attribute__((ext_vector_type(8))) __bf16 bf16x8_t;
typedef __attribute__((ext_vector_type(4))) float f32x4_t;

#define LOG2E 1.44269504f

static __device__ __forceinline__ u16 f2bf(float f) {
  union { float f; uint32_t u; } v; v.f = f;
  uint32_t r = v.u + 0x7FFFu + ((v.u >> 16) & 1u);
  return (u16)(r >> 16);
}

static __device__ __forceinline__ float bf2f(u16 h) {
  union { uint32_t u; float f; } v; v.u = ((uint32_t)h) << 16;
  return v.f;
}

static __device__ __forceinline__ uint32_t packbf2(float a, float b) {
  __hip_bfloat162 h2 = __float22bfloat162_rn(make_float2(a, b));
  union { __hip_bfloat162 hh; uint32_t u; } cvt; cvt.hh = h2;
  return cvt.u;
}

// raw v_exp_f32: computes 2^x in ONE instruction (no libm slow path)
static __device__ __forceinline__ float exp2_raw(float x) {
  float r;
  asm("v_exp_f32 %0, %1" : "=v"(r) : "v"(x));
  return r;
}

// async global->LDS, 16B per lane. LDS dest must be wave-uniform base + lane*16.
static __device__ __forceinline__ void async_copy16(const void* g, void* l) {
  __builtin_amdgcn_global_load_lds((const __attribute__((address_space(1))) void*)g,
                                   (__attribute__((address_space(3))) void*)l, 16, 0, 0);
}

// ---------------- fused prep: logf (blocks 0..4095) + weight transpose (blocks 4096..5119) ----------------
__global__ void prep_kernel(const float* __restrict__ x, const float* __restrict__ Wf,
                            float* __restrict__ lf, u16* __restrict__ xb,
                            const float* __restrict__ W0, const float* __restrict__ W1,
                            const float* __restrict__ W2, const float* __restrict__ W3,
                            u16* __restrict__ Wt) {
  __shared__ float xs[DD];
  __shared__ float part[16][17];
  __shared__ float tile[64][65];
  int t = threadIdx.x;  // 256
  if (blockIdx.x < 4096) {
    int row = blockIdx.x;   // b*N + n
    float4 v = *(const float4*)&x[(size_t)row * DD + t * 4];
    *(float4*)&xs[t * 4] = v;
    ushort4 o;
    o.x = f2bf(v.x); o.y = f2bf(v.y); o.z = f2bf(v.z); o.w = f2bf(v.w);
    *(ushort4*)&xb[(size_t)row * DD + t * 4] = o;
    __syncthreads();
    int h = t & 15, chunk = t >> 4;
    float s = 0.f;
#pragma unroll 8
    for (int e = 0; e < 64; e++)
      s += xs[chunk * 64 + e] * Wf[(chunk * 64 + e) * HH + h];
    part[chunk][h] = s;
    __syncthreads();
    if (t < 16) {
      float z = 0.f;
#pragma unroll
      for (int i = 0; i < 16; i++) z += part[i][t];
      float ls = fminf(z, 0.f) - log1pf(__expf(-fabsf(z)));
      int b = row >> 11, n = row & (NN - 1);
      lf[(b * HH + t) * NN + n] = ls;
    }
  } else {
    int bid = blockIdx.x - 4096;
    int wq = bid >> 8;  // which weight
    const float* W = wq == 0 ? W0 : wq == 1 ? W1 : wq == 2 ? W2 : W3;
    u16* out = Wt + (size_t)wq * DD * DD;
    int bx = bid & 15;          // n tile
    int by = (bid >> 4) & 15;   // k tile
    int c = t & 63, r4 = t >> 6;
#pragma unroll
    for (int i = 0; i < 16; i++) {
      int row = i * 4 + r4;
      tile[row][c] = W[(by * 64 + row) * DD + bx * 64 + c];
    }
    __syncthreads();
#pragma unroll
    for (int i = 0; i < 16; i++) {
      int row = i * 4 + r4;
      out[(bx * 64 + row) * DD + by * 64 + c] = f2bf(tile[c][row]);
    }
  }
}

// ---------------- cumsum over n per (b,h): float4/lane; OUTPUT PRE-SCALED by log2(e) ----------------
__global__ void cumsum_kernel(const float* __restrict__ lf, float* __restrict__ c) {
  int bh = blockIdx.x;
  int lane = threadIdx.x;  // 64
  const float* in = lf + bh * NN;
  float* out = c + bh * NN;
  float carry = 0.f;
  for (int t0 = 0; t0 < NN; t0 += 256) {
    float4 v = *(const float4*)&in[t0 + lane * 4];
    float s1 = v.x + v.y, s2 = s1 + v.z, s3 = s2 + v.w;
    float incl = s3;
#pragma unroll
    for (int off = 1; off < 64; off <<= 1) {
      float u = __shfl_up(incl, off, 64);
      if (lane >= off) incl += u;
    }
    float excl = incl - s3 + carry;
    float4 o;
    o.x = (excl + v.x) * LOG2E; o.y = (excl + s1) * LOG2E;
    o.z = (excl + s2) * LOG2E; o.w = (excl + s3) * LOG2E;
    *(float4*)&out[t0 + lane * 4] = o;
    carry = __shfl(incl, 63, 64) + carry;
  }
}

// ---------------- QKV GEMM 128x128 tile, BK=64, swizzled LDS, 512 threads (8 waves, 2x4) ----------------
__global__ __launch_bounds__(512, 4) void gemm_kernel(const u16* __restrict__ A,
                                                      const u16* __restrict__ Wt,
                                                      u16* __restrict__ oQ, u16* __restrict__ oK,
                                                      u16* __restrict__ oV) {
  __shared__ u16 Als[128 * 64];
  __shared__ u16 Bls[128 * 64];
  int m0 = blockIdx.y * 128, n0 = blockIdx.x * 128;
  int tid = threadIdx.x;
  int lane = tid & 63, w = tid >> 6;   // 8 waves
  int wm = w >> 2, wn = w & 3;         // 2 x 4 wave grid
  int lr = lane & 15, lg = lane >> 4;

  const u16* gA[2]; const u16* gB[2]; u16* lA[2]; u16* lB[2];
#pragma unroll
  for (int j = 0; j < 2; j++) {
    int s = tid + j * 512;
    int row = s >> 3, ch = s & 7;
    int scol = (ch ^ (row & 7)) * 8;
    gA[j] = &A [(size_t)(m0 + row) * DD + scol];
    gB[j] = &Wt[(size_t)(n0 + row) * DD + scol];
    lA[j] = &Als[s * 8];
    lB[j] = &Bls[s * 8];
  }

  f32x4_t acc[4][2];
#pragma unroll
  for (int i = 0; i < 4; i++)
#pragma unroll
    for (int j = 0; j < 2; j++) acc[i][j] = (f32x4_t){0.f, 0.f, 0.f, 0.f};

  for (int kt = 0; kt < DD; kt += 64) {
    __syncthreads();
#pragma unroll
    for (int j = 0; j < 2; j++) {
      async_copy16(gA[j] + kt, lA[j]);
      async_copy16(gB[j] + kt, lB[j]);
    }
    __syncthreads();
#pragma unroll
    for (int kk = 0; kk < 2; kk++) {
      bf16x8_t af[4], bfv[2];
#pragma unroll
      for (int mi = 0; mi < 4; mi++) {
        int row = wm * 64 + mi * 16 + lr;
        int boff = (row * 128 + kk * 64 + lg * 16) ^ ((row & 7) << 4);
        af[mi] = *(const bf16x8_t*)((const char*)Als + boff);
      }
#pragma unroll
      for (int ni = 0; ni < 2; ni++) {
        int row = wn * 32 + ni * 16 + lr;
        int boff = (row * 128 + kk * 64 + lg * 16) ^ ((row & 7) << 4);
        bfv[ni] = *(const bf16x8_t*)((const char*)Bls + boff);
      }
#pragma unroll
      for (int mi = 0; mi < 4; mi++)
#pragma unroll
        for (int ni = 0; ni < 2; ni++)
          acc[mi][ni] = __builtin_amdgcn_mfma_f32_16x16x32_bf16(af[mi], bfv[ni], acc[mi][ni], 0, 0, 0);
    }
  }

  int which = n0 >> 10;
  int nl0 = n0 & 1023;
  if (which == 2) {
#pragma unroll
    for (int mi = 0; mi < 4; mi++)
#pragma unroll
      for (int ni = 0; ni < 2; ni++) {
        int gcol = nl0 + wn * 32 + ni * 16 + lr;
        int h = gcol >> 6, hd = gcol & 63;
        int grow0 = m0 + wm * 64 + mi * 16 + lg * 4;
        int b = grow0 >> 11, n = grow0 & (NN - 1);
        ushort4 o4;
        o4.x = f2bf(acc[mi][ni][0]);
        o4.y = f2bf(acc[mi][ni][1]);
        o4.z = f2bf(acc[mi][ni][2]);
        o4.w = f2bf(acc[mi][ni][3]);
        *(ushort4*)&oV[((size_t)(b * HH + h) * HDD + hd) * NN + n] = o4;
      }
  } else {
    u16* outp = which == 0 ? oQ : oK;
#pragma unroll
    for (int mi = 0; mi < 4; mi++)
#pragma unroll
      for (int ni = 0; ni < 2; ni++) {
        int gcol = nl0 + wn * 32 + ni * 16 + lr;
        int h = gcol >> 6, hd = gcol & 63;
#pragma unroll
        for (int r = 0; r < 4; r++) {
          int grow = m0 + wm * 64 + mi * 16 + lg * 4 + r;
          int b = grow >> 11, n = grow & (NN - 1);
          outp[((size_t)(b * HH + h) * NN + n) * HDD + hd] = f2bf(acc[mi][ni][r]);
        }
      }
  }
}

// ---------------- out GEMM 128x64 tile, BK=64, grid 512 = 2 blocks/CU ----------------
__global__ __launch_bounds__(512, 4) void gemm_out_kernel(const u16* __restrict__ A,
                                                          const u16* __restrict__ Wt,
                                                          float* __restrict__ oF) {
  __shared__ u16 Als[128 * 64];
  __shared__ u16 Bls[64 * 64];
  int m0 = blockIdx.y * 128, n0 = blockIdx.x * 64;
  int tid = threadIdx.x;
  int lane = tid & 63, w = tid >> 6;
  int wm = w >> 2, wn = w & 3;
  int lr = lane & 15, lg = lane >> 4;

  const u16* gA[2]; u16* lA[2];
#pragma unroll
  for (int j = 0; j < 2; j++) {
    int s = tid + j * 512;
    int row = s >> 3, ch = s & 7;
    int scol = (ch ^ (row & 7)) * 8;
    gA[j] = &A[(size_t)(m0 + row) * DD + scol];
    lA[j] = &Als[s * 8];
  }
  int rowb = tid >> 3, chb = tid & 7;
  const u16* gB = &Wt[(size_t)(n0 + rowb) * DD + ((chb ^ (rowb & 7)) * 8)];
  u16* lB = &Bls[tid * 8];

  f32x4_t acc[4];
#pragma unroll
  for (int i = 0; i < 4; i++) acc[i] = (f32x4_t){0.f, 0.f, 0.f, 0.f};

  for (int kt = 0; kt < DD; kt += 64) {
    __syncthreads();
#pragma unroll
    for (int j = 0; j < 2; j++) async_copy16(gA[j] + kt, lA[j]);
    async_copy16(gB + kt, lB);
    __syncthreads();
#pragma unroll
    for (int kk = 0; kk < 2; kk++) {
      bf16x8_t af[4], bf1;
#pragma unroll
      for (int mi = 0; mi < 4; mi++) {
        int row = wm * 64 + mi * 16 + lr;
        int boff = (row * 128 + kk * 64 + lg * 16) ^ ((row & 7) << 4);
        af[mi] = *(const bf16x8_t*)((const char*)Als + boff);
      }
      {
        int row = wn * 16 + lr;
        int boff = (row * 128 + kk * 64 + lg * 16) ^ ((row & 7) << 4);
        bf1 = *(const bf16x8_t*)((const char*)Bls + boff);
      }
#pragma unroll
      for (int mi = 0; mi < 4; mi++)
        acc[mi] = __builtin_amdgcn_mfma_f32_16x16x32_bf16(af[mi], bf1, acc[mi], 0, 0, 0);
    }
  }

#pragma unroll
  for (int mi = 0; mi < 4; mi++) {
    int gcol = n0 + wn * 16 + lr;
#pragma unroll
    for (int r = 0; r < 4; r++) {
      int grow = m0 + wm * 64 + mi * 16 + lg * 4 + r;
      oF[(size_t)grow * DD + gcol] = acc[mi][r];
    }
  }
}

// ---------------- flash attention, KV-SPLIT: each (heavy,light) pair -> 2 blocks ----------------
// Fixed-max softmax is order-free: partial (oacc, lsum) over disjoint KV ranges add.
// split0 = first half of each tile's kv range (16 iter-units, uniform for all p);
// split1 = second half incl. diagonals (17 units). Grid 1024 = 4 blocks/CU (32KB LDS)
// -> 4 waves/SIMD at the stall points (vs 2). Partials: o bf16, lsum fp32 -> combine pass.
// Body = r14-proven: swapped QK^T, permlane P-in-reg, raw-v_exp exp2 softmax, dbuf staging.
__global__ __launch_bounds__(256) void attn_kernel(const u16* __restrict__ Q,
                                                   const u16* __restrict__ K,
                                                   const u16* __restrict__ Vt,
                                                   const float* __restrict__ cw,
                                                   u16* __restrict__ PO0, u16* __restrict__ PO1,
                                                   float* __restrict__ PL0, float* __restrict__ PL1) {
  __shared__ u16 Kls[2][KVBLK * 64];
  __shared__ u16 Vls[2][64 * KVBLK];
  int flat = blockIdx.x;                    // 1024
  int swz = (flat & 7) * 128 + (flat >> 3); // bijective; 4 bh per XCD
  int bh = swz >> 5;
  int pidx = (swz >> 1) & 15;
  int split = swz & 1;
  int tid = threadIdx.x;
  int lane = tid & 63, w = tid >> 6;
  int lr = lane & 15, lg = lane >> 4;
  const u16* Qh = Q + (size_t)bh * NN * HDD;
  const u16* Kh = K + (size_t)bh * NN * HDD;
  const u16* Vh = Vt + (size_t)bh * HDD * NN;
  const float* ch = cw + bh * NN;   // pre-scaled by log2e
  u16* po = split ? PO1 : PO0;
  float* pl = split ? PL1 : PL0;

  const float SCL = 0.125f * LOG2E;

  // staging geometry (r14-proven): swizzle folded into SOURCE chunk
  int s0 = tid, s1 = tid + 256;
  int r0 = s0 >> 3, p0 = s0 & 7;
  int r1 = s1 >> 3, p1 = s1 & 7;
  const u16* gk0 = &Kh[(size_t)r0 * HDD + ((p0 ^ (r0 & 7)) * 8)];
  const u16* gk1 = &Kh[(size_t)r1 * HDD + ((p1 ^ (r1 & 7)) * 8)];
  const u16* gv0 = &Vh[(size_t)r0 * NN + ((p0 ^ (r0 & 7)) * 8)];
  const u16* gv1 = &Vh[(size_t)r1 * NN + ((p1 ^ (r1 & 7)) * 8)];

  for (int which = 0; which < 2; which++) {
    int tile = which == 0 ? (31 - pidx) : pidx;
    int qb = tile * QBLK + w * 16;
    int iq = qb + lr;  // this lane's q-row

    int nt = tile + 1;
    int half = nt >> 1;
    int kstart = split ? half : 0;
    int kend   = split ? nt : half;

    bf16x8_t qf[2];
#pragma unroll
    for (int s = 0; s < 2; s++)
      qf[s] = *(const bf16x8_t*)&Qh[(size_t)iq * HDD + s * 32 + lg * 8];
    float cq = ch[iq];

    float lsum = 0.f;
    f32x4_t oacc[4];
#pragma unroll
    for (int fn = 0; fn < 4; fn++) oacc[fn] = (f32x4_t){0.f, 0.f, 0.f, 0.f};

    if (kstart < kend) {
      // prologue: stage kv tile kstart into buffer 0
      size_t kvs = (size_t)kstart * KVBLK;
      async_copy16(gk0 + kvs * HDD, &Kls[0][s0 * 8]);
      async_copy16(gk1 + kvs * HDD, &Kls[0][s1 * 8]);
      async_copy16(gv0 + kvs, &Vls[0][s0 * 8]);
      async_copy16(gv1 + kvs, &Vls[0][s1 * 8]);
      __syncthreads();

      int cur = 0;
      for (int kvt = kstart; kvt < kend; kvt++) {
        if (kvt + 1 < kend) {
          int nb = cur ^ 1;
          size_t kvn = (size_t)(kvt + 1) * KVBLK;
          async_copy16(gk0 + kvn * HDD, &Kls[nb][s0 * 8]);
          async_copy16(gk1 + kvn * HDD, &Kls[nb][s1 * 8]);
          async_copy16(gv0 + kvn, &Vls[nb][s0 * 8]);
          async_copy16(gv1 + kvn, &Vls[nb][s1 * 8]);
        }
        int kv0 = kvt * KVBLK;
        const u16* Kb = Kls[cur];
        const u16* Vb = Vls[cur];
        float4 ckv[4];
#pragma unroll
        for (int f = 0; f < 4; f++)
          ckv[f] = *(const float4*)&ch[kv0 + f * 16 + lg * 4];

        // S^T = K . Q^T
        f32x4_t sacc[4];
#pragma unroll
        for (int f = 0; f < 4; f++) sacc[f] = (f32x4_t){0.f, 0.f, 0.f, 0.f};
        __builtin_amdgcn_s_setprio(1);
#pragma unroll
        for (int f = 0; f < 4; f++) {
          int row = f * 16 + lr;
#pragma unroll
          for (int s = 0; s < 2; s++) {
            int boff = (row * 128 + s * 64 + lg * 16) ^ ((row & 7) << 4);
            bf16x8_t kf = *(const bf16x8_t*)((const char*)Kb + boff);
            sacc[f] = __builtin_amdgcn_mfma_f32_16x16x32_bf16(kf, qf[s], sacc[f], 0, 0, 0);
          }
        }
        __builtin_amdgcn_s_setprio(0);

        // fixed-max softmax, exp2 domain (raw v_exp); mask after exp
        bool diag = (kvt == nt - 1);
        float pv[4][4];
#pragma unroll
        for (int f = 0; f < 4; f++) {
          const float* ckp = &ckv[f].x;
#pragma unroll
          for (int r = 0; r < 4; r++) {
            float val = fmaf(sacc[f][r], SCL, cq - ckp[r]);
            float e = exp2_raw(val);
            if (diag && (kv0 + f * 16 + lg * 4 + r) > iq) e = 0.f;
            pv[f][r] = e; lsum += e;
          }
        }

        // pack P + permlane network -> B-fragments in regs
        bf16x8_t pa[2];
#pragma unroll
        for (int s = 0; s < 2; s++) {
          uint32_t x0 = packbf2(pv[2 * s][0], pv[2 * s][1]);
          uint32_t x1 = packbf2(pv[2 * s][2], pv[2 * s][3]);
          uint32_t y0 = packbf2(pv[2 * s + 1][0], pv[2 * s + 1][1]);
          uint32_t y1 = packbf2(pv[2 * s + 1][2], pv[2 * s + 1][3]);
          asm volatile("v_permlane32_swap_b32 %0, %1" : "+v"(x0), "+v"(y0));
          asm volatile("v_permlane32_swap_b32 %0, %1" : "+v"(x1), "+v"(y1));
          asm volatile("v_permlane16_swap_b32 %0, %1" : "+v"(x0), "+v"(y0));
          asm volatile("v_permlane16_swap_b32 %0, %1" : "+v"(x1), "+v"(y1));
          union { uint32_t u[4]; bf16x8_t v; } pk;
          pk.u[0] = x0; pk.u[1] = x1; pk.u[2] = y0; pk.u[3] = y1;
          pa[s] = pk.v;
        }

        // O^T += V^T . P
        __builtin_amdgcn_s_setprio(1);
#pragma unroll
        for (int fn = 0; fn < 4; fn++) {
          int row = fn * 16 + lr;
#pragma unroll
          for (int s = 0; s < 2; s++) {
            int boff = (row * 128 + s * 64 + lg * 16) ^ ((row & 7) << 4);
            bf16x8_t vf = *(const bf16x8_t*)((const char*)Vb + boff);
            oacc[fn] = __builtin_amdgcn_mfma_f32_16x16x32_bf16(vf, pa[s], oacc[fn], 0, 0, 0);
          }
        }
        __builtin_amdgcn_s_setprio(0);
        __syncthreads();
        cur ^= 1;
      }
    }

    // partial l: reduce over the 4 lg lanes sharing this q-row
    lsum += __shfl_xor(lsum, 16, 64);
    lsum += __shfl_xor(lsum, 32, 64);

    // write partials: o (bf16, unnormalized), lsum (fp32)
    size_t rowbase = ((size_t)bh * NN + iq) * HDD;
#pragma unroll
    for (int fn = 0; fn < 4; fn++) {
      ushort4 o4;
      o4.x = f2bf(oacc[fn][0]);
      o4.y = f2bf(oacc[fn][1]);
      o4.z = f2bf(oacc[fn][2]);
      o4.w = f2bf(oacc[fn][3]);
      *(ushort4*)&po[rowbase + fn * 16 + lg * 4] = o4;
    }
    if (lg == 0) pl[(size_t)bh * NN + iq] = lsum;
  }
}

// ---------------- combine partials: O = (o0+o1)/(l0+l1), bf16 [b n d] ----------------
__global__ void combine_kernel(const u16* __restrict__ PO0, const u16* __restrict__ PO1,
                               const float* __restrict__ PL0, const float* __restrict__ PL1,
                               u16* __restrict__ O) {
  int gi = blockIdx.x * 256 + threadIdx.x;   // 524288 threads
  int rowid = gi >> 3, seg = gi & 7;         // rowid = bh*2048 + n; seg = 8-elem hd chunk
  uint4 a = *(const uint4*)&PO0[(size_t)rowid * HDD + seg * 8];
  uint4 bq = *(const uint4*)&PO1[(size_t)rowid * HDD + seg * 8];
  float rinv = 1.0f / (PL0[rowid] + PL1[rowid]);
  const uint32_t* aw = &a.x; const uint32_t* bw = &bq.x;
  union { u16 v[8]; uint4 q; } out;
#pragma unroll
  for (int i = 0; i < 4; i++) {
    float f0 = (bf2f((u16)aw[i]) + bf2f((u16)bw[i])) * rinv;
    float f1 = (bf2f((u16)(aw[i] >> 16)) + bf2f((u16)(bw[i] >> 16))) * rinv;
    out.v[2 * i] = f2bf(f0);
    out.v[2 * i + 1] = f2bf(f1);
  }
  int bh = rowid >> 11, n = rowid & (NN - 1);
  int b = bh >> 4, h = bh & 15;
  *(uint4*)&O[((size_t)(b * NN + n)) * DD + h * HDD + seg * 8] = out.q;
}

extern "C" void kernel_launch(void* const* d_in, const int* in_sizes, int n_in,
                              void* d_out, int out_size, void* d_ws, size_t ws_size,
                              hipStream_t stream) {
  const float* x  = (const float*)d_in[0];
  const float* Wq = (const float*)d_in[1];
  const float* Wk = (const float*)d_in[2];
  const float* Wv = (const float*)d_in[3];
  const float* Wo = (const float*)d_in[4];
  const float* Wf = (const float*)d_in[5];
  float* out = (float*)d_out;
  char* ws = (char*)d_ws;
  const size_t MB = 1024 * 1024;
  u16* x_bf  = (u16*)(ws + 0);        // 8 MB (dead after gemm_qkv -> reused as PO0)
  u16* WqkvT = (u16*)(ws + 8 * MB);   // 6 MB QKV thirds (dead after gemm_qkv; PL0 reuses first 256KB) + 2MB WoT at 14MB (live)
  u16* Qw    = (u16*)(ws + 16 * MB);  // 8 MB [bh][n][hd]
  u16* Kw    = (u16*)(ws + 24 * MB);  // 8 MB
  u16* Vw    = (u16*)(ws + 32 * MB);  // 8 MB [bh][hd][n] (written transposed by gemm)
  u16* Ow    = (u16*)(ws + 40 * MB);  // 8 MB [b n d]
  float* lf  = (float*)(ws + 48 * MB);             // 256 KB
  float* cwp = (float*)(ws + 48 * MB + 262144);    // 256 KB (pre-scaled by log2e)
  float* PL1 = (float*)(ws + 48 * MB + 524288);    // 256 KB
  u16* PO1   = (u16*)(ws + 49 * MB);               // 8 MB (ws usage tops at 57MB, round-1 proven)
  u16* PO0   = x_bf;                               // alias: dead after gemm_qkv
  float* PL0 = (float*)(ws + 8 * MB);              // alias: WqkvT Q-third, dead after gemm_qkv

  // fused prep: logf+cast (4096 blocks) || weight transpose (1024 blocks)
  prep_kernel<<<5120, 256, 0, stream>>>(x, Wf, lf, x_bf, Wq, Wk, Wv, Wo, WqkvT);
  cumsum_kernel<<<32, 64, 0, stream>>>(lf, cwp);
  // fused QKV GEMM: N = 3072; V written directly transposed
  gemm_kernel<<<dim3(24, 32), 512, 0, stream>>>(x_bf, WqkvT, Qw, Kw, Vw);
  // kv-split attention: 1024 blocks (4/CU), partial outputs
  attn_kernel<<<1024, 256, 0, stream>>>(Qw, Kw, Vw, cwp, PO0, PO1, PL0, PL1);
  combine_kernel<<<2048, 256, 0, stream>>>(PO0, PO1, PL0, PL1, Ow);
  gemm_out_kernel<<<dim3(16, 32), 512, 0, stream>>>(Ow, WqkvT + (size_t)3 * DD * DD, out);
}

// Round 18
// 120.824 us; speedup vs baseline: 1.0289x; 1.0289x over previous
//
#include <hip/hip_runtime.h>
#include <hip/hip_bf16.h>
#include <stdint.h>

#define NN 2048
#define DD 1024
#define HH 16
#define HDD 64
#define QBLK 64
#define KVBLK 128

typedef unsigned short u16;
typedef __attribute__((ext_vector_type(8))) __bf16 bf16x8_t;
typedef __attribute__((ext_vector_type(4))) float f32x4_t;

#define LOG2E 1.44269504f

static __device__ __forceinline__ u16 f2bf(float f) {
  union { float f; uint32_t u; } v; v.f = f;
  uint32_t r = v.u + 0x7FFFu + ((v.u >> 16) & 1u);
  return (u16)(r >> 16);
}

static __device__ __forceinline__ uint32_t packbf2(float a, float b) {
  __hip_bfloat162 h2 = __float22bfloat162_rn(make_float2(a, b));
  union { __hip_bfloat162 hh; uint32_t u; } cvt; cvt.hh = h2;
  return cvt.u;
}

// raw v_exp_f32: computes 2^x in ONE instruction (no libm slow path)
static __device__ __forceinline__ float exp2_raw(float x) {
  float r;
  asm("v_exp_f32 %0, %1" : "=v"(r) : "v"(x));
  return r;
}

// async global->LDS, 16B per lane. LDS dest must be wave-uniform base + lane*16.
static __device__ __forceinline__ void async_copy16(const void* g, void* l) {
  __builtin_amdgcn_global_load_lds((const __attribute__((address_space(1))) void*)g,
                                   (__attribute__((address_space(3))) void*)l, 16, 0, 0);
}

// ---------------- fused prep: logf (blocks 0..4095) + weight transpose (blocks 4096..5119) ----------------
__global__ void prep_kernel(const float* __restrict__ x, const float* __restrict__ Wf,
                            float* __restrict__ lf, u16* __restrict__ xb,
                            const float* __restrict__ W0, const float* __restrict__ W1,
                            const float* __restrict__ W2, const float* __restrict__ W3,
                            u16* __restrict__ Wt) {
  __shared__ float xs[DD];
  __shared__ float part[16][17];
  __shared__ float tile[64][65];
  int t = threadIdx.x;  // 256
  if (blockIdx.x < 4096) {
    int row = blockIdx.x;   // b*N + n
    float4 v = *(const float4*)&x[(size_t)row * DD + t * 4];
    *(float4*)&xs[t * 4] = v;
    ushort4 o;
    o.x = f2bf(v.x); o.y = f2bf(v.y); o.z = f2bf(v.z); o.w = f2bf(v.w);
    *(ushort4*)&xb[(size_t)row * DD + t * 4] = o;
    __syncthreads();
    int h = t & 15, chunk = t >> 4;
    float s = 0.f;
#pragma unroll 8
    for (int e = 0; e < 64; e++)
      s += xs[chunk * 64 + e] * Wf[(chunk * 64 + e) * HH + h];
    part[chunk][h] = s;
    __syncthreads();
    if (t < 16) {
      float z = 0.f;
#pragma unroll
      for (int i = 0; i < 16; i++) z += part[i][t];
      float ls = fminf(z, 0.f) - log1pf(__expf(-fabsf(z)));
      int b = row >> 11, n = row & (NN - 1);
      lf[(b * HH + t) * NN + n] = ls;
    }
  } else {
    int bid = blockIdx.x - 4096;
    int wq = bid >> 8;  // which weight
    const float* W = wq == 0 ? W0 : wq == 1 ? W1 : wq == 2 ? W2 : W3;
    u16* out = Wt + (size_t)wq * DD * DD;
    int bx = bid & 15;          // n tile
    int by = (bid >> 4) & 15;   // k tile
    int c = t & 63, r4 = t >> 6;
#pragma unroll
    for (int i = 0; i < 16; i++) {
      int row = i * 4 + r4;
      tile[row][c] = W[(by * 64 + row) * DD + bx * 64 + c];
    }
    __syncthreads();
#pragma unroll
    for (int i = 0; i < 16; i++) {
      int row = i * 4 + r4;
      out[(bx * 64 + row) * DD + by * 64 + c] = f2bf(tile[c][row]);
    }
  }
}

// ---------------- cumsum over n per (b,h): float4/lane; OUTPUT PRE-SCALED by log2(e) ----------------
__global__ void cumsum_kernel(const float* __restrict__ lf, float* __restrict__ c) {
  int bh = blockIdx.x;
  int lane = threadIdx.x;  // 64
  const float* in = lf + bh * NN;
  float* out = c + bh * NN;
  float carry = 0.f;
  for (int t0 = 0; t0 < NN; t0 += 256) {
    float4 v = *(const float4*)&in[t0 + lane * 4];
    float s1 = v.x + v.y, s2 = s1 + v.z, s3 = s2 + v.w;
    float incl = s3;
#pragma unroll
    for (int off = 1; off < 64; off <<= 1) {
      float u = __shfl_up(incl, off, 64);
      if (lane >= off) incl += u;
    }
    float excl = incl - s3 + carry;
    float4 o;
    o.x = (excl + v.x) * LOG2E; o.y = (excl + s1) * LOG2E;
    o.z = (excl + s2) * LOG2E; o.w = (excl + s3) * LOG2E;
    *(float4*)&out[t0 + lane * 4] = o;
    carry = __shfl(incl, 63, 64) + carry;
  }
}

// ---------------- QKV GEMM 128x128 tile, BK=64, swizzled LDS, 512 threads (8 waves, 2x4) ----------------
// Wt is [3072][1024]. V third (unswapped mfma): [bh][hd][n] packed stores. Q/K thirds:
// SWAPPED mfma operands -> D^T (col=token, row=model-dim) -> per lane 4 consecutive hd
// at one token -> packed 8B stores to [bh][n][hd] (was 16x 2B scalar scatter).
__global__ __launch_bounds__(512, 4) void gemm_kernel(const u16* __restrict__ A,
                                                      const u16* __restrict__ Wt,
                                                      u16* __restrict__ oQ, u16* __restrict__ oK,
                                                      u16* __restrict__ oV) {
  __shared__ u16 Als[128 * 64];
  __shared__ u16 Bls[128 * 64];
  int m0 = blockIdx.y * 128, n0 = blockIdx.x * 128;
  int tid = threadIdx.x;
  int lane = tid & 63, w = tid >> 6;   // 8 waves
  int wm = w >> 2, wn = w & 3;         // 2 x 4 wave grid
  int lr = lane & 15, lg = lane >> 4;
  int which = n0 >> 10;
  bool isV = (which == 2);

  const u16* gA[2]; const u16* gB[2]; u16* lA[2]; u16* lB[2];
#pragma unroll
  for (int j = 0; j < 2; j++) {
    int s = tid + j * 512;
    int row = s >> 3, ch = s & 7;
    int scol = (ch ^ (row & 7)) * 8;
    gA[j] = &A [(size_t)(m0 + row) * DD + scol];
    gB[j] = &Wt[(size_t)(n0 + row) * DD + scol];
    lA[j] = &Als[s * 8];
    lB[j] = &Bls[s * 8];
  }

  f32x4_t acc[4][2];
#pragma unroll
  for (int i = 0; i < 4; i++)
#pragma unroll
    for (int j = 0; j < 2; j++) acc[i][j] = (f32x4_t){0.f, 0.f, 0.f, 0.f};

  for (int kt = 0; kt < DD; kt += 64) {
    __syncthreads();
#pragma unroll
    for (int j = 0; j < 2; j++) {
      async_copy16(gA[j] + kt, lA[j]);
      async_copy16(gB[j] + kt, lB[j]);
    }
    __syncthreads();
#pragma unroll
    for (int kk = 0; kk < 2; kk++) {
      bf16x8_t af[4], bfv[2];
#pragma unroll
      for (int mi = 0; mi < 4; mi++) {
        int row = wm * 64 + mi * 16 + lr;
        int boff = (row * 128 + kk * 64 + lg * 16) ^ ((row & 7) << 4);
        af[mi] = *(const bf16x8_t*)((const char*)Als + boff);
      }
#pragma unroll
      for (int ni = 0; ni < 2; ni++) {
        int row = wn * 32 + ni * 16 + lr;
        int boff = (row * 128 + kk * 64 + lg * 16) ^ ((row & 7) << 4);
        bfv[ni] = *(const bf16x8_t*)((const char*)Bls + boff);
      }
      if (isV) {
#pragma unroll
        for (int mi = 0; mi < 4; mi++)
#pragma unroll
          for (int ni = 0; ni < 2; ni++)
            acc[mi][ni] = __builtin_amdgcn_mfma_f32_16x16x32_bf16(af[mi], bfv[ni], acc[mi][ni], 0, 0, 0);
      } else {
#pragma unroll
        for (int mi = 0; mi < 4; mi++)
#pragma unroll
          for (int ni = 0; ni < 2; ni++)
            acc[mi][ni] = __builtin_amdgcn_mfma_f32_16x16x32_bf16(bfv[ni], af[mi], acc[mi][ni], 0, 0, 0);
      }
    }
  }

  int nl0 = n0 & 1023;
  if (isV) {
    // V (unswapped): D col = model-dim, rows = 4 consecutive tokens -> [bh][hd][n] packed 8B
#pragma unroll
    for (int mi = 0; mi < 4; mi++)
#pragma unroll
      for (int ni = 0; ni < 2; ni++) {
        int gcol = nl0 + wn * 32 + ni * 16 + lr;
        int h = gcol >> 6, hd = gcol & 63;
        int grow0 = m0 + wm * 64 + mi * 16 + lg * 4;
        int b = grow0 >> 11, n = grow0 & (NN - 1);
        ushort4 o4;
        o4.x = f2bf(acc[mi][ni][0]);
        o4.y = f2bf(acc[mi][ni][1]);
        o4.z = f2bf(acc[mi][ni][2]);
        o4.w = f2bf(acc[mi][ni][3]);
        *(ushort4*)&oV[((size_t)(b * HH + h) * HDD + hd) * NN + n] = o4;
      }
  } else {
    // Q/K (swapped): D^T col = token (lr), rows = 4 consecutive model dims -> [bh][n][hd] packed 8B
    u16* outp = which == 0 ? oQ : oK;
#pragma unroll
    for (int mi = 0; mi < 4; mi++)
#pragma unroll
      for (int ni = 0; ni < 2; ni++) {
        int n_tok = m0 + wm * 64 + mi * 16 + lr;
        int b = n_tok >> 11, n = n_tok & (NN - 1);
        int gmod = nl0 + wn * 32 + ni * 16 + lg * 4;
        int h = gmod >> 6, hd = gmod & 63;
        ushort4 o4;
        o4.x = f2bf(acc[mi][ni][0]);
        o4.y = f2bf(acc[mi][ni][1]);
        o4.z = f2bf(acc[mi][ni][2]);
        o4.w = f2bf(acc[mi][ni][3]);
        *(ushort4*)&outp[((size_t)(b * HH + h) * NN + n) * HDD + hd] = o4;
      }
  }
}

// ---------------- out GEMM 128x64 tile, BK=64, grid 512 = 2 blocks/CU ----------------
__global__ __launch_bounds__(512, 4) void gemm_out_kernel(const u16* __restrict__ A,
                                                          const u16* __restrict__ Wt,
                                                          float* __restrict__ oF) {
  __shared__ u16 Als[128 * 64];
  __shared__ u16 Bls[64 * 64];
  int m0 = blockIdx.y * 128, n0 = blockIdx.x * 64;
  int tid = threadIdx.x;
  int lane = tid & 63, w = tid >> 6;
  int wm = w >> 2, wn = w & 3;
  int lr = lane & 15, lg = lane >> 4;

  const u16* gA[2]; u16* lA[2];
#pragma unroll
  for (int j = 0; j < 2; j++) {
    int s = tid + j * 512;
    int row = s >> 3, ch = s & 7;
    int scol = (ch ^ (row & 7)) * 8;
    gA[j] = &A[(size_t)(m0 + row) * DD + scol];
    lA[j] = &Als[s * 8];
  }
  int rowb = tid >> 3, chb = tid & 7;
  const u16* gB = &Wt[(size_t)(n0 + rowb) * DD + ((chb ^ (rowb & 7)) * 8)];
  u16* lB = &Bls[tid * 8];

  f32x4_t acc[4];
#pragma unroll
  for (int i = 0; i < 4; i++) acc[i] = (f32x4_t){0.f, 0.f, 0.f, 0.f};

  for (int kt = 0; kt < DD; kt += 64) {
    __syncthreads();
#pragma unroll
    for (int j = 0; j < 2; j++) async_copy16(gA[j] + kt, lA[j]);
    async_copy16(gB + kt, lB);
    __syncthreads();
#pragma unroll
    for (int kk = 0; kk < 2; kk++) {
      bf16x8_t af[4], bf1;
#pragma unroll
      for (int mi = 0; mi < 4; mi++) {
        int row = wm * 64 + mi * 16 + lr;
        int boff = (row * 128 + kk * 64 + lg * 16) ^ ((row & 7) << 4);
        af[mi] = *(const bf16x8_t*)((const char*)Als + boff);
      }
      {
        int row = wn * 16 + lr;
        int boff = (row * 128 + kk * 64 + lg * 16) ^ ((row & 7) << 4);
        bf1 = *(const bf16x8_t*)((const char*)Bls + boff);
      }
#pragma unroll
      for (int mi = 0; mi < 4; mi++)
        acc[mi] = __builtin_amdgcn_mfma_f32_16x16x32_bf16(af[mi], bf1, acc[mi], 0, 0, 0);
    }
  }

#pragma unroll
  for (int mi = 0; mi < 4; mi++) {
    int gcol = n0 + wn * 16 + lr;
#pragma unroll
    for (int r = 0; r < 4; r++) {
      int grow = m0 + wm * 64 + mi * 16 + lg * 4 + r;
      oF[(size_t)grow * DD + gcol] = acc[mi][r];
    }
  }
}

// ---------------- flash attention: KVBLK=128, PEELED diagonal (mask ops only on last kv tile) ----------------
// Paired q-tiles (31-p then p), nt=(tile>>1)+1 per tile (uniform 17 iters/pair).
// Loop body inlined twice via lambda: masked=false hot path has NO cmp/cndmask (VALU cut,
// r17 lesson: attn is VALU/issue-throughput-bound). Raw-v_exp exp2 softmax; dbuf staging.
__global__ __launch_bounds__(256) void attn_kernel(const u16* __restrict__ Q,
                                                   const u16* __restrict__ K,
                                                   const u16* __restrict__ Vt,
                                                   const float* __restrict__ cw,
                                                   u16* __restrict__ O) {
  __shared__ u16 Kls[2][KVBLK * 64];   // [128 kv rows][64 hd], 16KB each
  __shared__ u16 Vls[2][64 * KVBLK];   // [64 hd][128 kv], 16KB each
  int flat = blockIdx.y * gridDim.x + blockIdx.x;  // grid (16, 32) = 512
  int swz = (flat & 7) * 64 + (flat >> 3);         // bijective, bh-contiguous per XCD
  int pidx = swz & 15, bh = swz >> 4;
  int tid = threadIdx.x;
  int lane = tid & 63, w = tid >> 6;
  int lr = lane & 15, lg = lane >> 4;
  const u16* Qh = Q + (size_t)bh * NN * HDD;
  const u16* Kh = K + (size_t)bh * NN * HDD;
  const u16* Vh = Vt + (size_t)bh * HDD * NN;
  const float* ch = cw + bh * NN;   // pre-scaled by log2e
  int b = bh >> 4, h = bh & 15;

  const float SCL = 0.125f * LOG2E;

  // staging: K tile = 1024 slots of 16B (row=s>>3, chunk=s&7); V tile = 1024 slots
  // (row=s>>4, chunk=s&15). LDS linear at slot*16B; swizzle folded into SOURCE chunk.
  const u16* gk[4]; const u16* gv[4];
#pragma unroll
  for (int j = 0; j < 4; j++) {
    int s = tid + j * 256;
    int kr = s >> 3, kc = s & 7;
    gk[j] = &Kh[(size_t)kr * HDD + ((kc ^ (kr & 7)) * 8)];
    int vr = s >> 4, vc = s & 15;
    gv[j] = &Vh[(size_t)vr * NN + ((vc ^ (vr & 7)) * 8)];
  }

  for (int which = 0; which < 2; which++) {
    int tile = which == 0 ? (31 - pidx) : pidx;
    int qb = tile * QBLK + w * 16;
    int iq = qb + lr;  // this lane's q-row

    bf16x8_t qf[2];
#pragma unroll
    for (int s = 0; s < 2; s++)
      qf[s] = *(const bf16x8_t*)&Qh[(size_t)iq * HDD + s * 32 + lg * 8];
    float cq = ch[iq];

    float lsum = 0.f;
    f32x4_t oacc[4];
#pragma unroll
    for (int fn = 0; fn < 4; fn++) oacc[fn] = (f32x4_t){0.f, 0.f, 0.f, 0.f};

    int nt = (tile >> 1) + 1;

    // prologue: stage kv tile 0 into buffer 0
#pragma unroll
    for (int j = 0; j < 4; j++) {
      int s = tid + j * 256;
      async_copy16(gk[j], &Kls[0][s * 8]);
      async_copy16(gv[j], &Vls[0][s * 8]);
    }
    __syncthreads();

    // compute body; `masked` is a literal at each call site -> cndmask DCE'd when false
    auto body = [&](int kvt, int bufc, bool masked) {
      int kv0 = kvt * KVBLK;
      const u16* Kb = Kls[bufc];
      const u16* Vb = Vls[bufc];
      float4 ckv[8];
#pragma unroll
      for (int f = 0; f < 8; f++)
        ckv[f] = *(const float4*)&ch[kv0 + f * 16 + lg * 4];

      f32x4_t sacc[8];
#pragma unroll
      for (int f = 0; f < 8; f++) sacc[f] = (f32x4_t){0.f, 0.f, 0.f, 0.f};
      __builtin_amdgcn_s_setprio(1);
#pragma unroll
      for (int f = 0; f < 8; f++) {
        int row = f * 16 + lr;
#pragma unroll
        for (int s = 0; s < 2; s++) {
          int boff = (row * 128 + s * 64 + lg * 16) ^ ((row & 7) << 4);
          bf16x8_t kf = *(const bf16x8_t*)((const char*)Kb + boff);
          sacc[f] = __builtin_amdgcn_mfma_f32_16x16x32_bf16(kf, qf[s], sacc[f], 0, 0, 0);
        }
      }
      __builtin_amdgcn_s_setprio(0);

      float pv[8][4];
#pragma unroll
      for (int f = 0; f < 8; f++) {
        const float* ckp = &ckv[f].x;
#pragma unroll
        for (int r = 0; r < 4; r++) {
          float val = fmaf(sacc[f][r], SCL, cq - ckp[r]);
          float e = exp2_raw(val);
          if (masked && (kv0 + f * 16 + lg * 4 + r) > iq) e = 0.f;
          pv[f][r] = e; lsum += e;
        }
      }

      bf16x8_t pa[4];
#pragma unroll
      for (int s = 0; s < 4; s++) {
        uint32_t x0 = packbf2(pv[2 * s][0], pv[2 * s][1]);
        uint32_t x1 = packbf2(pv[2 * s][2], pv[2 * s][3]);
        uint32_t y0 = packbf2(pv[2 * s + 1][0], pv[2 * s + 1][1]);
        uint32_t y1 = packbf2(pv[2 * s + 1][2], pv[2 * s + 1][3]);
        asm volatile("v_permlane32_swap_b32 %0, %1" : "+v"(x0), "+v"(y0));
        asm volatile("v_permlane32_swap_b32 %0, %1" : "+v"(x1), "+v"(y1));
        asm volatile("v_permlane16_swap_b32 %0, %1" : "+v"(x0), "+v"(y0));
        asm volatile("v_permlane16_swap_b32 %0, %1" : "+v"(x1), "+v"(y1));
        union { uint32_t u[4]; bf16x8_t v; } pk;
        pk.u[0] = x0; pk.u[1] = x1; pk.u[2] = y0; pk.u[3] = y1;
        pa[s] = pk.v;
      }

      __builtin_amdgcn_s_setprio(1);
#pragma unroll
      for (int fn = 0; fn < 4; fn++) {
        int row = fn * 16 + lr;
#pragma unroll
        for (int s = 0; s < 4; s++) {
          int boff = row * 256 + ((s * 64 + lg * 16) ^ ((row & 7) << 4));
          bf16x8_t vf = *(const bf16x8_t*)((const char*)Vb + boff);
          oacc[fn] = __builtin_amdgcn_mfma_f32_16x16x32_bf16(vf, pa[s], oacc[fn], 0, 0, 0);
        }
      }
      __builtin_amdgcn_s_setprio(0);
    };

    int cur = 0;
    for (int kvt = 0; kvt < nt - 1; kvt++) {
      // stage next tile (always valid: kvt+1 <= nt-1)
      int nb = cur ^ 1;
      size_t kvn = (size_t)(kvt + 1) * KVBLK;
#pragma unroll
      for (int j = 0; j < 4; j++) {
        int s = tid + j * 256;
        async_copy16(gk[j] + kvn * HDD, &Kls[nb][s * 8]);
        async_copy16(gv[j] + kvn, &Vls[nb][s * 8]);
      }
      body(kvt, cur, false);   // hot path: no mask ops
      __syncthreads();
      cur ^= 1;
    }
    body(nt - 1, cur, true);   // peeled diagonal iteration
    __syncthreads();

    // l-reduce over the 4 lanes sharing lr
    lsum += __shfl_xor(lsum, 16, 64);
    lsum += __shfl_xor(lsum, 32, 64);
    float rinv = 1.0f / lsum;

    // output: lane's q-row iq, hd = fn*16 + lg*4 + r -> packed 8B stores
    u16* orow = O + ((size_t)(b * NN + iq)) * DD + h * HDD;
#pragma unroll
    for (int fn = 0; fn < 4; fn++) {
      ushort4 o4;
      o4.x = f2bf(oacc[fn][0] * rinv);
      o4.y = f2bf(oacc[fn][1] * rinv);
      o4.z = f2bf(oacc[fn][2] * rinv);
      o4.w = f2bf(oacc[fn][3] * rinv);
      *(ushort4*)&orow[fn * 16 + lg * 4] = o4;
    }
  }
}

extern "C" void kernel_launch(void* const* d_in, const int* in_sizes, int n_in,
                              void* d_out, int out_size, void* d_ws, size_t ws_size,
                              hipStream_t stream) {
  const float* x  = (const float*)d_in[0];
  const float* Wq = (const float*)d_in[1];
  const float* Wk = (const float*)d_in[2];
  const float* Wv = (const float*)d_in[3];
  const float* Wo = (const float*)d_in[4];
  const float* Wf = (const float*)d_in[5];
  float* out = (float*)d_out;
  char* ws = (char*)d_ws;
  const size_t MB = 1024 * 1024;
  u16* x_bf  = (u16*)(ws + 0);        // 8 MB
  u16* WqkvT = (u16*)(ws + 8 * MB);   // 6 MB: WqT | WkT | WvT contiguous [3072][1024]; WoT follows
  u16* Qw    = (u16*)(ws + 16 * MB);  // 8 MB [bh][n][hd]
  u16* Kw    = (u16*)(ws + 24 * MB);  // 8 MB
  u16* Vw    = (u16*)(ws + 32 * MB);  // 8 MB [bh][hd][n] (written transposed by gemm)
  u16* Ow    = (u16*)(ws + 40 * MB);  // 8 MB [b n d]
  float* lf  = (float*)(ws + 48 * MB);            // 256 KB
  float* cwp = (float*)(ws + 48 * MB + 262144);   // 256 KB (pre-scaled by log2e)

  // fused prep: logf+cast (4096 blocks) || weight transpose (1024 blocks)
  prep_kernel<<<5120, 256, 0, stream>>>(x, Wf, lf, x_bf, Wq, Wk, Wv, Wo, WqkvT);
  cumsum_kernel<<<32, 64, 0, stream>>>(lf, cwp);
  // fused QKV GEMM: N = 3072; V written transposed; Q/K via swapped-operand packed stores
  gemm_kernel<<<dim3(24, 32), 512, 0, stream>>>(x_bf, WqkvT, Qw, Kw, Vw);
  attn_kernel<<<dim3(16, 32), 256, 0, stream>>>(Qw, Kw, Vw, cwp, Ow);
  gemm_out_kernel<<<dim3(16, 32), 512, 0, stream>>>(Ow, WqkvT + (size_t)3 * DD * DD, out);
}

// Round 19
// 119.152 us; speedup vs baseline: 1.0433x; 1.0140x over previous
//
#include <hip/hip_runtime.h>
#include <hip/hip_bf16.h>
#include <stdint.h>

#define NN 2048
#define DD 1024
#define HH 16
#define HDD 64
#define QBLK 64
#define KVBLK 128

typedef unsigned short u16;
typedef __attribute__((ext_vector_type(8))) __bf16 bf16x8_t;
typedef __attribute__((ext_vector_type(4))) float f32x4_t;

#define LOG2E 1.44269504f

static __device__ __forceinline__ u16 f2bf(float f) {
  union { float f; uint32_t u; } v; v.f = f;
  uint32_t r = v.u + 0x7FFFu + ((v.u >> 16) & 1u);
  return (u16)(r >> 16);
}

static __device__ __forceinline__ uint32_t packbf2(float a, float b) {
  __hip_bfloat162 h2 = __float22bfloat162_rn(make_float2(a, b));
  union { __hip_bfloat162 hh; uint32_t u; } cvt; cvt.hh = h2;
  return cvt.u;
}

// raw v_exp_f32: computes 2^x in ONE instruction (no libm slow path)
static __device__ __forceinline__ float exp2_raw(float x) {
  float r;
  asm("v_exp_f32 %0, %1" : "=v"(r) : "v"(x));
  return r;
}

// async global->LDS, 16B per lane. LDS dest must be wave-uniform base + lane*16.
static __device__ __forceinline__ void async_copy16(const void* g, void* l) {
  __builtin_amdgcn_global_load_lds((const __attribute__((address_space(1))) void*)g,
                                   (__attribute__((address_space(3))) void*)l, 16, 0, 0);
}

// ---------------- fused prep: logf (blocks 0..4095) + weight transpose (blocks 4096..5119) ----------------
__global__ void prep_kernel(const float* __restrict__ x, const float* __restrict__ Wf,
                            float* __restrict__ lf, u16* __restrict__ xb,
                            const float* __restrict__ W0, const float* __restrict__ W1,
                            const float* __restrict__ W2, const float* __restrict__ W3,
                            u16* __restrict__ Wt) {
  __shared__ float xs[DD];
  __shared__ float part[16][17];
  __shared__ float tile[64][65];
  int t = threadIdx.x;  // 256
  if (blockIdx.x < 4096) {
    int row = blockIdx.x;   // b*N + n
    float4 v = *(const float4*)&x[(size_t)row * DD + t * 4];
    *(float4*)&xs[t * 4] = v;
    ushort4 o;
    o.x = f2bf(v.x); o.y = f2bf(v.y); o.z = f2bf(v.z); o.w = f2bf(v.w);
    *(ushort4*)&xb[(size_t)row * DD + t * 4] = o;
    __syncthreads();
    int h = t & 15, chunk = t >> 4;
    float s = 0.f;
#pragma unroll 8
    for (int e = 0; e < 64; e++)
      s += xs[chunk * 64 + e] * Wf[(chunk * 64 + e) * HH + h];
    part[chunk][h] = s;
    __syncthreads();
    if (t < 16) {
      float z = 0.f;
#pragma unroll
      for (int i = 0; i < 16; i++) z += part[i][t];
      float ls = fminf(z, 0.f) - log1pf(__expf(-fabsf(z)));
      int b = row >> 11, n = row & (NN - 1);
      lf[(b * HH + t) * NN + n] = ls;
    }
  } else {
    int bid = blockIdx.x - 4096;
    int wq = bid >> 8;  // which weight
    const float* W = wq == 0 ? W0 : wq == 1 ? W1 : wq == 2 ? W2 : W3;
    u16* out = Wt + (size_t)wq * DD * DD;
    int bx = bid & 15;          // n tile
    int by = (bid >> 4) & 15;   // k tile
    int c = t & 63, r4 = t >> 6;
#pragma unroll
    for (int i = 0; i < 16; i++) {
      int row = i * 4 + r4;
      tile[row][c] = W[(by * 64 + row) * DD + bx * 64 + c];
    }
    __syncthreads();
#pragma unroll
    for (int i = 0; i < 16; i++) {
      int row = i * 4 + r4;
      out[(bx * 64 + row) * DD + by * 64 + c] = f2bf(tile[c][row]);
    }
  }
}

// ---------------- cumsum over n per (b,h): float4/lane; OUTPUT PRE-SCALED by log2(e) ----------------
__global__ void cumsum_kernel(const float* __restrict__ lf, float* __restrict__ c) {
  int bh = blockIdx.x;
  int lane = threadIdx.x;  // 64
  const float* in = lf + bh * NN;
  float* out = c + bh * NN;
  float carry = 0.f;
  for (int t0 = 0; t0 < NN; t0 += 256) {
    float4 v = *(const float4*)&in[t0 + lane * 4];
    float s1 = v.x + v.y, s2 = s1 + v.z, s3 = s2 + v.w;
    float incl = s3;
#pragma unroll
    for (int off = 1; off < 64; off <<= 1) {
      float u = __shfl_up(incl, off, 64);
      if (lane >= off) incl += u;
    }
    float excl = incl - s3 + carry;
    float4 o;
    o.x = (excl + v.x) * LOG2E; o.y = (excl + s1) * LOG2E;
    o.z = (excl + s2) * LOG2E; o.w = (excl + s3) * LOG2E;
    *(float4*)&out[t0 + lane * 4] = o;
    carry = __shfl(incl, 63, 64) + carry;
  }
}

// ---------------- QKV GEMM 128x128 tile, BK=64, swizzled LDS, 512 threads (r16-proven form) ----------------
// Wt is [3072][1024]; Q/K -> [bh][n][hd] bf16; V -> [bh][hd][n] bf16 (fused transpose)
__global__ __launch_bounds__(512, 4) void gemm_kernel(const u16* __restrict__ A,
                                                      const u16* __restrict__ Wt,
                                                      u16* __restrict__ oQ, u16* __restrict__ oK,
                                                      u16* __restrict__ oV) {
  __shared__ u16 Als[128 * 64];
  __shared__ u16 Bls[128 * 64];
  int m0 = blockIdx.y * 128, n0 = blockIdx.x * 128;
  int tid = threadIdx.x;
  int lane = tid & 63, w = tid >> 6;   // 8 waves
  int wm = w >> 2, wn = w & 3;         // 2 x 4 wave grid
  int lr = lane & 15, lg = lane >> 4;

  const u16* gA[2]; const u16* gB[2]; u16* lA[2]; u16* lB[2];
#pragma unroll
  for (int j = 0; j < 2; j++) {
    int s = tid + j * 512;
    int row = s >> 3, ch = s & 7;
    int scol = (ch ^ (row & 7)) * 8;
    gA[j] = &A [(size_t)(m0 + row) * DD + scol];
    gB[j] = &Wt[(size_t)(n0 + row) * DD + scol];
    lA[j] = &Als[s * 8];
    lB[j] = &Bls[s * 8];
  }

  f32x4_t acc[4][2];
#pragma unroll
  for (int i = 0; i < 4; i++)
#pragma unroll
    for (int j = 0; j < 2; j++) acc[i][j] = (f32x4_t){0.f, 0.f, 0.f, 0.f};

  for (int kt = 0; kt < DD; kt += 64) {
    __syncthreads();
#pragma unroll
    for (int j = 0; j < 2; j++) {
      async_copy16(gA[j] + kt, lA[j]);
      async_copy16(gB[j] + kt, lB[j]);
    }
    __syncthreads();
#pragma unroll
    for (int kk = 0; kk < 2; kk++) {
      bf16x8_t af[4], bfv[2];
#pragma unroll
      for (int mi = 0; mi < 4; mi++) {
        int row = wm * 64 + mi * 16 + lr;
        int boff = (row * 128 + kk * 64 + lg * 16) ^ ((row & 7) << 4);
        af[mi] = *(const bf16x8_t*)((const char*)Als + boff);
      }
#pragma unroll
      for (int ni = 0; ni < 2; ni++) {
        int row = wn * 32 + ni * 16 + lr;
        int boff = (row * 128 + kk * 64 + lg * 16) ^ ((row & 7) << 4);
        bfv[ni] = *(const bf16x8_t*)((const char*)Bls + boff);
      }
#pragma unroll
      for (int mi = 0; mi < 4; mi++)
#pragma unroll
        for (int ni = 0; ni < 2; ni++)
          acc[mi][ni] = __builtin_amdgcn_mfma_f32_16x16x32_bf16(af[mi], bfv[ni], acc[mi][ni], 0, 0, 0);
    }
  }

  int which = n0 >> 10;
  int nl0 = n0 & 1023;
  if (which == 2) {
    // V: write transposed [bh][hd][n] -- 4 consecutive n per thread = packed 8B store
#pragma unroll
    for (int mi = 0; mi < 4; mi++)
#pragma unroll
      for (int ni = 0; ni < 2; ni++) {
        int gcol = nl0 + wn * 32 + ni * 16 + lr;
        int h = gcol >> 6, hd = gcol & 63;
        int grow0 = m0 + wm * 64 + mi * 16 + lg * 4;
        int b = grow0 >> 11, n = grow0 & (NN - 1);
        ushort4 o4;
        o4.x = f2bf(acc[mi][ni][0]);
        o4.y = f2bf(acc[mi][ni][1]);
        o4.z = f2bf(acc[mi][ni][2]);
        o4.w = f2bf(acc[mi][ni][3]);
        *(ushort4*)&oV[((size_t)(b * HH + h) * HDD + hd) * NN + n] = o4;
      }
  } else {
    u16* outp = which == 0 ? oQ : oK;
#pragma unroll
    for (int mi = 0; mi < 4; mi++)
#pragma unroll
      for (int ni = 0; ni < 2; ni++) {
        int gcol = nl0 + wn * 32 + ni * 16 + lr;
        int h = gcol >> 6, hd = gcol & 63;
#pragma unroll
        for (int r = 0; r < 4; r++) {
          int grow = m0 + wm * 64 + mi * 16 + lg * 4 + r;
          int b = grow >> 11, n = grow & (NN - 1);
          outp[((size_t)(b * HH + h) * NN + n) * HDD + hd] = f2bf(acc[mi][ni][r]);
        }
      }
  }
}

// ---------------- out GEMM 128x64 tile, BK=64, grid 512 = 2 blocks/CU ----------------
__global__ __launch_bounds__(512, 4) void gemm_out_kernel(const u16* __restrict__ A,
                                                          const u16* __restrict__ Wt,
                                                          float* __restrict__ oF) {
  __shared__ u16 Als[128 * 64];
  __shared__ u16 Bls[64 * 64];
  int m0 = blockIdx.y * 128, n0 = blockIdx.x * 64;
  int tid = threadIdx.x;
  int lane = tid & 63, w = tid >> 6;
  int wm = w >> 2, wn = w & 3;
  int lr = lane & 15, lg = lane >> 4;

  const u16* gA[2]; u16* lA[2];
#pragma unroll
  for (int j = 0; j < 2; j++) {
    int s = tid + j * 512;
    int row = s >> 3, ch = s & 7;
    int scol = (ch ^ (row & 7)) * 8;
    gA[j] = &A[(size_t)(m0 + row) * DD + scol];
    lA[j] = &Als[s * 8];
  }
  int rowb = tid >> 3, chb = tid & 7;
  const u16* gB = &Wt[(size_t)(n0 + rowb) * DD + ((chb ^ (rowb & 7)) * 8)];
  u16* lB = &Bls[tid * 8];

  f32x4_t acc[4];
#pragma unroll
  for (int i = 0; i < 4; i++) acc[i] = (f32x4_t){0.f, 0.f, 0.f, 0.f};

  for (int kt = 0; kt < DD; kt += 64) {
    __syncthreads();
#pragma unroll
    for (int j = 0; j < 2; j++) async_copy16(gA[j] + kt, lA[j]);
    async_copy16(gB + kt, lB);
    __syncthreads();
#pragma unroll
    for (int kk = 0; kk < 2; kk++) {
      bf16x8_t af[4], bf1;
#pragma unroll
      for (int mi = 0; mi < 4; mi++) {
        int row = wm * 64 + mi * 16 + lr;
        int boff = (row * 128 + kk * 64 + lg * 16) ^ ((row & 7) << 4);
        af[mi] = *(const bf16x8_t*)((const char*)Als + boff);
      }
      {
        int row = wn * 16 + lr;
        int boff = (row * 128 + kk * 64 + lg * 16) ^ ((row & 7) << 4);
        bf1 = *(const bf16x8_t*)((const char*)Bls + boff);
      }
#pragma unroll
      for (int mi = 0; mi < 4; mi++)
        acc[mi] = __builtin_amdgcn_mfma_f32_16x16x32_bf16(af[mi], bf1, acc[mi], 0, 0, 0);
    }
  }

#pragma unroll
  for (int mi = 0; mi < 4; mi++) {
    int gcol = n0 + wn * 16 + lr;
#pragma unroll
    for (int r = 0; r < 4; r++) {
      int grow = m0 + wm * 64 + mi * 16 + lg * 4 + r;
      oF[(size_t)grow * DD + gcol] = acc[mi][r];
    }
  }
}

// ---------------- flash attention: KVBLK=128, peeled diagonal, HOISTED LDS ADDRESSING ----------------
// XOR mask bits (4-6) are disjoint from f*2048 / lr*128 / lr*256 (bits >=7), so the swizzle
// distributes: boff = [(s*64+lg*16)^msk] + lr*{128,256} + {f*2048|fn*4096}. Precompute the
// per-lane swizzled constants once; every ds_read becomes base + compile-time immediate ->
// compiler folds into ds_read offset:N (addressing VALU ~40 -> ~12 per iter; r17/r18 lesson:
// attn is VALU/issue-bound). Raw-v_exp exp2 softmax, dbuf global_load_lds staging.
__global__ __launch_bounds__(256) void attn_kernel(const u16* __restrict__ Q,
                                                   const u16* __restrict__ K,
                                                   const u16* __restrict__ Vt,
                                                   const float* __restrict__ cw,
                                                   u16* __restrict__ O) {
  __shared__ u16 Kls[2][KVBLK * 64];   // [128 kv rows][64 hd], 16KB each
  __shared__ u16 Vls[2][64 * KVBLK];   // [64 hd][128 kv], 16KB each
  int flat = blockIdx.y * gridDim.x + blockIdx.x;  // grid (16, 32) = 512
  int swz = (flat & 7) * 64 + (flat >> 3);         // bijective, bh-contiguous per XCD
  int pidx = swz & 15, bh = swz >> 4;
  int tid = threadIdx.x;
  int lane = tid & 63, w = tid >> 6;
  int lr = lane & 15, lg = lane >> 4;
  const u16* Qh = Q + (size_t)bh * NN * HDD;
  const u16* Kh = K + (size_t)bh * NN * HDD;
  const u16* Vh = Vt + (size_t)bh * HDD * NN;
  const float* ch = cw + bh * NN;   // pre-scaled by log2e
  int b = bh >> 4, h = bh & 15;

  const float SCL = 0.125f * LOG2E;

  // per-lane swizzled sub-row offsets (bits 0-7), disjoint from row/f components
  int msk = (lr & 7) << 4;
  int sw0 = (0 * 64 + lg * 16) ^ msk;
  int sw1 = (1 * 64 + lg * 16) ^ msk;
  int sw2 = (2 * 64 + lg * 16) ^ msk;
  int sw3 = (3 * 64 + lg * 16) ^ msk;

  // staging: K tile = 1024 slots of 16B (row=s>>3, chunk=s&7); V tile = 1024 slots
  // (row=s>>4, chunk=s&15). LDS linear at slot*16B; swizzle folded into SOURCE chunk.
  const u16* gk[4]; const u16* gv[4];
#pragma unroll
  for (int j = 0; j < 4; j++) {
    int s = tid + j * 256;
    int kr = s >> 3, kc = s & 7;
    gk[j] = &Kh[(size_t)kr * HDD + ((kc ^ (kr & 7)) * 8)];
    int vr = s >> 4, vc = s & 15;
    gv[j] = &Vh[(size_t)vr * NN + ((vc ^ (vr & 7)) * 8)];
  }

  for (int which = 0; which < 2; which++) {
    int tile = which == 0 ? (31 - pidx) : pidx;
    int qb = tile * QBLK + w * 16;
    int iq = qb + lr;  // this lane's q-row

    bf16x8_t qf[2];
#pragma unroll
    for (int s = 0; s < 2; s++)
      qf[s] = *(const bf16x8_t*)&Qh[(size_t)iq * HDD + s * 32 + lg * 8];
    float cq = ch[iq];

    float lsum = 0.f;
    f32x4_t oacc[4];
#pragma unroll
    for (int fn = 0; fn < 4; fn++) oacc[fn] = (f32x4_t){0.f, 0.f, 0.f, 0.f};

    int nt = (tile >> 1) + 1;

    // prologue: stage kv tile 0 into buffer 0
#pragma unroll
    for (int j = 0; j < 4; j++) {
      int s = tid + j * 256;
      async_copy16(gk[j], &Kls[0][s * 8]);
      async_copy16(gv[j], &Vls[0][s * 8]);
    }
    __syncthreads();

    // compute body; masked literal at call site -> cndmask DCE'd in hot path
    auto body = [&](int kvt, int bufc, bool masked) {
      int kv0 = kvt * KVBLK;
      // base pointers with swizzle folded; all reads at compile-time imm offsets
      const char* kp0 = (const char*)Kls[bufc] + lr * 128 + sw0;
      const char* kp1 = (const char*)Kls[bufc] + lr * 128 + sw1;
      const char* vp0 = (const char*)Vls[bufc] + lr * 256 + sw0;
      const char* vp1 = (const char*)Vls[bufc] + lr * 256 + sw1;
      const char* vp2 = (const char*)Vls[bufc] + lr * 256 + sw2;
      const char* vp3 = (const char*)Vls[bufc] + lr * 256 + sw3;
      float4 ckv[8];
#pragma unroll
      for (int f = 0; f < 8; f++)
        ckv[f] = *(const float4*)&ch[kv0 + f * 16 + lg * 4];

      f32x4_t sacc[8];
#pragma unroll
      for (int f = 0; f < 8; f++) sacc[f] = (f32x4_t){0.f, 0.f, 0.f, 0.f};
      __builtin_amdgcn_s_setprio(1);
#pragma unroll
      for (int f = 0; f < 8; f++) {
        bf16x8_t k0 = *(const bf16x8_t*)(kp0 + f * 2048);
        bf16x8_t k1 = *(const bf16x8_t*)(kp1 + f * 2048);
        sacc[f] = __builtin_amdgcn_mfma_f32_16x16x32_bf16(k0, qf[0], sacc[f], 0, 0, 0);
        sacc[f] = __builtin_amdgcn_mfma_f32_16x16x32_bf16(k1, qf[1], sacc[f], 0, 0, 0);
      }
      __builtin_amdgcn_s_setprio(0);

      float pv[8][4];
#pragma unroll
      for (int f = 0; f < 8; f++) {
        const float* ckp = &ckv[f].x;
#pragma unroll
        for (int r = 0; r < 4; r++) {
          float val = fmaf(sacc[f][r], SCL, cq - ckp[r]);
          float e = exp2_raw(val);
          if (masked && (kv0 + f * 16 + lg * 4 + r) > iq) e = 0.f;
          pv[f][r] = e; lsum += e;
        }
      }

      bf16x8_t pa[4];
#pragma unroll
      for (int s = 0; s < 4; s++) {
        uint32_t x0 = packbf2(pv[2 * s][0], pv[2 * s][1]);
        uint32_t x1 = packbf2(pv[2 * s][2], pv[2 * s][3]);
        uint32_t y0 = packbf2(pv[2 * s + 1][0], pv[2 * s + 1][1]);
        uint32_t y1 = packbf2(pv[2 * s + 1][2], pv[2 * s + 1][3]);
        asm volatile("v_permlane32_swap_b32 %0, %1" : "+v"(x0), "+v"(y0));
        asm volatile("v_permlane32_swap_b32 %0, %1" : "+v"(x1), "+v"(y1));
        asm volatile("v_permlane16_swap_b32 %0, %1" : "+v"(x0), "+v"(y0));
        asm volatile("v_permlane16_swap_b32 %0, %1" : "+v"(x1), "+v"(y1));
        union { uint32_t u[4]; bf16x8_t v; } pk;
        pk.u[0] = x0; pk.u[1] = x1; pk.u[2] = y0; pk.u[3] = y1;
        pa[s] = pk.v;
      }

      __builtin_amdgcn_s_setprio(1);
#pragma unroll
      for (int fn = 0; fn < 4; fn++) {
        bf16x8_t v0 = *(const bf16x8_t*)(vp0 + fn * 4096);
        bf16x8_t v1 = *(const bf16x8_t*)(vp1 + fn * 4096);
        bf16x8_t v2 = *(const bf16x8_t*)(vp2 + fn * 4096);
        bf16x8_t v3 = *(const bf16x8_t*)(vp3 + fn * 4096);
        oacc[fn] = __builtin_amdgcn_mfma_f32_16x16x32_bf16(v0, pa[0], oacc[fn], 0, 0, 0);
        oacc[fn] = __builtin_amdgcn_mfma_f32_16x16x32_bf16(v1, pa[1], oacc[fn], 0, 0, 0);
        oacc[fn] = __builtin_amdgcn_mfma_f32_16x16x32_bf16(v2, pa[2], oacc[fn], 0, 0, 0);
        oacc[fn] = __builtin_amdgcn_mfma_f32_16x16x32_bf16(v3, pa[3], oacc[fn], 0, 0, 0);
      }
      __builtin_amdgcn_s_setprio(0);
    };

    int cur = 0;
    for (int kvt = 0; kvt < nt - 1; kvt++) {
      int nb = cur ^ 1;
      size_t kvn = (size_t)(kvt + 1) * KVBLK;
#pragma unroll
      for (int j = 0; j < 4; j++) {
        int s = tid + j * 256;
        async_copy16(gk[j] + kvn * HDD, &Kls[nb][s * 8]);
        async_copy16(gv[j] + kvn, &Vls[nb][s * 8]);
      }
      body(kvt, cur, false);   // hot path: no mask ops
      __syncthreads();
      cur ^= 1;
    }
    body(nt - 1, cur, true);   // peeled diagonal iteration
    __syncthreads();

    // l-reduce over the 4 lanes sharing lr
    lsum += __shfl_xor(lsum, 16, 64);
    lsum += __shfl_xor(lsum, 32, 64);
    float rinv = 1.0f / lsum;

    // output: lane's q-row iq, hd = fn*16 + lg*4 + r -> packed 8B stores
    u16* orow = O + ((size_t)(b * NN + iq)) * DD + h * HDD;
#pragma unroll
    for (int fn = 0; fn < 4; fn++) {
      ushort4 o4;
      o4.x = f2bf(oacc[fn][0] * rinv);
      o4.y = f2bf(oacc[fn][1] * rinv);
      o4.z = f2bf(oacc[fn][2] * rinv);
      o4.w = f2bf(oacc[fn][3] * rinv);
      *(ushort4*)&orow[fn * 16 + lg * 4] = o4;
    }
  }
}

extern "C" void kernel_launch(void* const* d_in, const int* in_sizes, int n_in,
                              void* d_out, int out_size, void* d_ws, size_t ws_size,
                              hipStream_t stream) {
  const float* x  = (const float*)d_in[0];
  const float* Wq = (const float*)d_in[1];
  const float* Wk = (const float*)d_in[2];
  const float* Wv = (const float*)d_in[3];
  const float* Wo = (const float*)d_in[4];
  const float* Wf = (const float*)d_in[5];
  float* out = (float*)d_out;
  char* ws = (char*)d_ws;
  const size_t MB = 1024 * 1024;
  u16* x_bf  = (u16*)(ws + 0);        // 8 MB
  u16* WqkvT = (u16*)(ws + 8 * MB);   // 6 MB: WqT | WkT | WvT contiguous [3072][1024]; WoT follows
  u16* Qw    = (u16*)(ws + 16 * MB);  // 8 MB [bh][n][hd]
  u16* Kw    = (u16*)(ws + 24 * MB);  // 8 MB
  u16* Vw    = (u16*)(ws + 32 * MB);  // 8 MB [bh][hd][n] (written transposed by gemm)
  u16* Ow    = (u16*)(ws + 40 * MB);  // 8 MB [b n d]
  float* lf  = (float*)(ws + 48 * MB);            // 256 KB
  float* cwp = (float*)(ws + 48 * MB + 262144);   // 256 KB (pre-scaled by log2e)

  // fused prep: logf+cast (4096 blocks) || weight transpose (1024 blocks)
  prep_kernel<<<5120, 256, 0, stream>>>(x, Wf, lf, x_bf, Wq, Wk, Wv, Wo, WqkvT);
  cumsum_kernel<<<32, 64, 0, stream>>>(lf, cwp);
  // fused QKV GEMM: N = 3072; V written directly transposed
  gemm_kernel<<<dim3(24, 32), 512, 0, stream>>>(x_bf, WqkvT, Qw, Kw, Vw);
  attn_kernel<<<dim3(16, 32), 256, 0, stream>>>(Qw, Kw, Vw, cwp, Ow);
  gemm_out_kernel<<<dim3(16, 32), 512, 0, stream>>>(Ow, WqkvT + (size_t)3 * DD * DD, out);
}